// Round 2
// baseline (470.829 us; speedup 1.0000x reference)
//
#include <hip/hip_runtime.h>
#include <hip/hip_bf16.h>

// GCN over Block-CSR adjacency. ALL I/O BUFFERS ARE FLOAT32 (reference dtypes).
// Compute: bf16 MFMA, fp32 accumulate; intermediates stored bf16.
//
// Round 8: spmm_ln v5 — LDS-staged gathers via global_load_lds.
// Evidence: R6 (VGPR=64) and R7 (VGPR=124 despite 256 budget + sched_barrier
// fences) both show the compiler serializes register-held gathers. Fix: hold
// in-flight gather data in LDS via global_load_lds (no dest regs -> nothing to
// serialize; depth bounded by vmcnt/LDS only).
//  - WG = 4 waves = 1 block-row; wave q owns cols [64q, 64q+64).
//  - Per row/wave: 16 DMAs x 1KB into private 16KB LDS slice (per-lane gather
//    source, lane-linear dest = exactly the MFMA B-frag layout) + 8 A dwordx4
//    to regs -> vmcnt(0) -> 16 ds_read_b128 + 16 MFMA.
//  - Next row's DMAs issued right after the MFMA block (slots provably free:
//    all ds_reads retired before last MFMA issues) -> LN hides DMA latency.
//  - LN partials: shfl reduce + parity-double-buffered LDS exchange + RAW
//    s_barrier (lgkmcnt-only drain; __syncthreads would vmcnt(0)-drain the
//    prefetch queue).
//  - LDS 66.5KB/WG -> 2 WG/CU; ~24 outstanding loads/wave at zero VGPR cost.
//
// z_bt layout: per 16-row block rb, store [F][16] so SpMM B-fragments are 16B loads.
// d_ws: zbt + h (bf16) = exactly 128 MiB. Transposed bf16 weights (229 KB) in
// d_out-as-scratch; consumed before spmm_out overwrites d_out (stream-ordered).

typedef __bf16 bf16;
typedef bf16 bf16x8 __attribute__((ext_vector_type(8)));
typedef bf16 bf16x4 __attribute__((ext_vector_type(4)));
typedef float f32x4 __attribute__((ext_vector_type(4)));

#define N_NODES 131072
#define BRQ 8192      // block rows (= N/16)
#define KNZ 8         // nonzero blocks per block row
#define IN_F 128
#define HID 256
#define NCLS 64

#define SB() __builtin_amdgcn_sched_barrier(0)

static __device__ __forceinline__ f32x4 mfma16(bf16x8 a, bf16x8 b, f32x4 c) {
  return __builtin_amdgcn_mfma_f32_16x16x32_bf16(a, b, c, 0, 0, 0);
}

static __device__ __forceinline__ bf16x8 load8(const bf16* p) {
  return *(const bf16x8*)p;
}
static __device__ __forceinline__ bf16x8 cvt8(f32x4 a0, f32x4 a1) {
  bf16x8 r;
  r[0] = (bf16)a0[0]; r[1] = (bf16)a0[1]; r[2] = (bf16)a0[2]; r[3] = (bf16)a0[3];
  r[4] = (bf16)a1[0]; r[5] = (bf16)a1[1]; r[6] = (bf16)a1[2]; r[7] = (bf16)a1[3];
  return r;
}
static __device__ __forceinline__ bf16x8 load8(const float* p) {
  f32x4 a0 = *(const f32x4*)p;
  f32x4 a1 = *(const f32x4*)(p + 4);
  return cvt8(a0, a1);
}

static __device__ __forceinline__ void dma16(const char* gsrc, char* ldst) {
  __builtin_amdgcn_global_load_lds(
      (const __attribute__((address_space(1))) void*)gsrc,
      (__attribute__((address_space(3))) void*)ldst, 16, 0, 0);
}

// ---------------- fused transpose + f32->bf16 convert for all 3 W matrices -------
// sizes: W0 128x256 (32768), W1 256x256 (65536), W2 256x64 (16384) => 114688 elems
__global__ void transpose_all(const float* __restrict__ W0, const float* __restrict__ W1,
                              const float* __restrict__ W2, bf16* __restrict__ w0t,
                              bf16* __restrict__ w1t, bf16* __restrict__ w2t) {
  int idx = blockIdx.x * 256 + threadIdx.x;
  if (idx < 32768) {
    int r = idx >> 8, c = idx & 255;            // 128 x 256
    w0t[c * 128 + r] = (bf16)W0[idx];
  } else if (idx < 98304) {
    int j = idx - 32768; int r = j >> 8, c = j & 255;  // 256 x 256
    w1t[c * 256 + r] = (bf16)W1[j];
  } else {
    int j = idx - 98304; int r = j >> 6, c = j & 63;   // 256 x 64
    w2t[c * 256 + r] = (bf16)W2[j];
  }
}

// ---------------- dense GEMM: B-stationary registers ------------------------------
// Zbt[rt][col][r] = X[N,KIN] @ W[KIN,FOUT]; WT = W^T [FOUT,KIN] bf16 row-major.
template<typename TA, int KIN, int FOUT, int GRID>
__global__ __launch_bounds__(256) void gemm_bt(const TA* __restrict__ X,
                                               const bf16* __restrict__ WT,
                                               bf16* __restrict__ Zbt) {
  constexpr int CG  = FOUT / 64;          // 64-col groups
  constexpr int KS  = KIN / 32;           // K steps
  constexpr int RTS = GRID * 4 / CG;      // row-tile stride (waves per col group)
  constexpr int NT  = BRQ / RTS;          // row-tiles per wave

  const int wave = threadIdx.x >> 6;
  const int lane = threadIdx.x & 63;
  const int l15  = lane & 15;
  const int quad = lane >> 4;
  const int gw   = blockIdx.x * 4 + wave;
  const int cg   = gw % CG;
  const int rt0  = gw / CG;

  const bf16* __restrict__ wbase = WT + (long)(cg * 64 + l15) * KIN + quad * 8;
  bf16x8 bfr[KS][4];
#pragma unroll
  for (int k = 0; k < KS; ++k)
#pragma unroll
    for (int t = 0; t < 4; ++t)
      bfr[k][t] = *(const bf16x8*)(wbase + t * (16 * KIN) + k * 32);

  const TA* __restrict__ xbase = X + (long)l15 * KIN + quad * 8;

  bf16x8 aw[2][KS];
#pragma unroll
  for (int k = 0; k < KS; ++k)
    aw[0][k] = load8(xbase + (long)rt0 * (16 * KIN) + k * 32);

#pragma unroll
  for (int it = 0; it < NT; ++it) {
    const int rt = rt0 + it * RTS;
    if (it + 1 < NT) {
      const long xoff = (long)(rt + RTS) * (16 * KIN);
#pragma unroll
      for (int k = 0; k < KS; ++k)
        aw[(it + 1) & 1][k] = load8(xbase + xoff + k * 32);
    }
    f32x4 acc[4] = {};
#pragma unroll
    for (int k = 0; k < KS; ++k)
#pragma unroll
      for (int t = 0; t < 4; ++t)
        acc[t] = mfma16(aw[it & 1][k], bfr[k][t], acc[t]);
#pragma unroll
    for (int t = 0; t < 4; ++t) {
      int col = cg * 64 + t * 16 + l15;
      bf16x4 v;
#pragma unroll
      for (int i = 0; i < 4; ++i) v[i] = (bf16)acc[t][i];
      *(bf16x4*)(Zbt + ((long)rt * FOUT + col) * 16 + quad * 4) = v;
    }
  }
}

// ---------------- SpMM + bias + ReLU + LayerNorm (F = HID = 256) v5 ---------------
// WG = 4 waves = one block-row; wave q covers cols [q*64, q*64+64).
// Gathers staged in LDS via global_load_lds (per-lane source, lane-linear dest).
#define RPW 8   // block-rows per workgroup

__global__ __launch_bounds__(256) void spmm_ln(const float* __restrict__ Abv,
                                               const int*   __restrict__ Abc,
                                               const bf16*  __restrict__ Zbt,
                                               const float* __restrict__ bias,
                                               const float* __restrict__ gamma,
                                               const float* __restrict__ beta,
                                               bf16* __restrict__ H) {
  const int wave = threadIdx.x >> 6;       // col quarter
  const int lane = threadIdx.x & 63;
  const int l15  = lane & 15;
  const int quad = lane >> 4;
  const int half = quad >> 1;              // which of the 2 blocks per MFMA k=32
  const int kb   = (quad & 1) * 16;        // byte offset along k (8 elems * 2B)

  __shared__ __align__(16) char stage[4][16 * 1024];   // 16KB per wave
  __shared__ float S[2][4][16], SS[2][4][16];          // parity LN exchange

  char* wbuf = &stage[wave][0];
  const char* zbase = (const char*)Zbt;
  // per-lane byte offset inside a gathered z-block: col f = wave*64 + t*16 + l15,
  // element (f,k) at byte f*32 + k*2 (block is [256][16] bf16 = 8192 B).
  const unsigned fbyte = (unsigned)((wave * 64 + l15) * 32) + (unsigned)kb;

  // hoisted per-f constants (invariant across rows)
  float bi[4], gv[4], bvv[4];
#pragma unroll
  for (int t = 0; t < 4; ++t) {
    int f = wave * 64 + t * 16 + l15;
    bi[t] = bias[f]; gv[t] = gamma[f]; bvv[t] = beta[f];
  }

  const int b0 = blockIdx.x * RPW;

  // ---- prologue: row b0 DMAs + A loads ----
  f32x4 ar[4][2];
  {
    const int*   bc    = Abc + b0 * KNZ;
    const float* abase = Abv + (long)b0 * (KNZ * 256) + l15 * 16 + (quad & 1) * 8;
#pragma unroll
    for (int kp = 0; kp < 4; ++kp) {
      const char* src = zbase + (long)bc[2 * kp + half] * 8192 + fbyte;
#pragma unroll
      for (int t = 0; t < 4; ++t)
        dma16(src + t * 512, wbuf + (kp * 4 + t) * 1024);
      const float* p = abase + (2 * kp + half) * 256;
      ar[kp][0] = *(const f32x4*)p;
      ar[kp][1] = *(const f32x4*)(p + 4);
    }
  }

#pragma unroll
  for (int it = 0; it < RPW; ++it) {
    const int b = b0 + it;

    // next-row addresses early (scalar/VALU work during the drain window)
    long zoffn[4];
    const float* abn = Abv;
    if (it + 1 < RPW) {
      const int* bc = Abc + (b + 1) * KNZ;
#pragma unroll
      for (int kp = 0; kp < 4; ++kp)
        zoffn[kp] = (long)bc[2 * kp + half] * 8192;
      abn = Abv + (long)(b + 1) * (KNZ * 256) + l15 * 16 + (quad & 1) * 8;
    }

    // drain current row's DMAs + A loads (single wait per row)
    asm volatile("s_waitcnt vmcnt(0)" ::: "memory");

    bf16x8 afr[4];
#pragma unroll
    for (int kp = 0; kp < 4; ++kp) afr[kp] = cvt8(ar[kp][0], ar[kp][1]);

    f32x4 acc[4] = {};
#pragma unroll
    for (int kp = 0; kp < 4; ++kp)
#pragma unroll
      for (int t = 0; t < 4; ++t) {
        bf16x8 bf = *(const bf16x8*)(wbuf + (kp * 4 + t) * 1024 + lane * 16);
        acc[t] = mfma16(afr[kp], bf, acc[t]);
      }

    // issue next row's DMAs + A loads; LN below hides their latency.
    // LDS slots are free: every ds_read retired before the last MFMA issued.
    SB();
    if (it + 1 < RPW) {
#pragma unroll
      for (int kp = 0; kp < 4; ++kp) {
        const char* src = zbase + zoffn[kp] + fbyte;
#pragma unroll
        for (int t = 0; t < 4; ++t)
          dma16(src + t * 512, wbuf + (kp * 4 + t) * 1024);
        const float* p = abn + (2 * kp + half) * 256;
        ar[kp][0] = *(const f32x4*)p;
        ar[kp][1] = *(const f32x4*)(p + 4);
      }
    }
    SB();

    // bias + relu + per-row partial sums
    float ps[4] = {0.f, 0.f, 0.f, 0.f}, pss[4] = {0.f, 0.f, 0.f, 0.f};
#pragma unroll
    for (int t = 0; t < 4; ++t)
#pragma unroll
      for (int i = 0; i < 4; ++i) {
        float v = acc[t][i] + bi[t];
        v = v > 0.f ? v : 0.f;
        acc[t][i] = v;
        ps[i] += v;
        pss[i] += v * v;
      }
    // reduce across the 16 lanes of this quad (rows quad*4+i)
#pragma unroll
    for (int m = 1; m < 16; m <<= 1) {
#pragma unroll
      for (int i = 0; i < 4; ++i) {
        ps[i]  += __shfl_xor(ps[i], m, 64);
        pss[i] += __shfl_xor(pss[i], m, 64);
      }
    }
    const int par = it & 1;
    if (l15 == 0) {
#pragma unroll
      for (int i = 0; i < 4; ++i) {
        S[par][wave][quad * 4 + i]  = ps[i];
        SS[par][wave][quad * 4 + i] = pss[i];
      }
    }
    // raw barrier: drain LDS writes only; DMA queue stays alive.
    SB();
    asm volatile("s_waitcnt lgkmcnt(0)" ::: "memory");
    __builtin_amdgcn_s_barrier();
    SB();

    // combine 4 wave-partials, normalize, store
#pragma unroll
    for (int i = 0; i < 4; ++i) {
      int r = quad * 4 + i;
      float s  = S[par][0][r] + S[par][1][r] + S[par][2][r] + S[par][3][r];
      float ss = SS[par][0][r] + SS[par][1][r] + SS[par][2][r] + SS[par][3][r];
      float mu   = s * (1.f / 256.f);
      float var  = ss * (1.f / 256.f) - mu * mu;
      float rstd = rsqrtf(var + 1e-5f);
      bf16* hrow = H + (long)(b * 16 + r) * HID + wave * 64;
#pragma unroll
      for (int t = 0; t < 4; ++t) {
        float y = (acc[t][i] - mu) * rstd * gv[t] + bvv[t];
        hrow[t * 16 + l15] = (bf16)y;
      }
    }
    SB();
  }
}

// ---------------- final SpMM + bias (F = NCLS = 64), row-major FLOAT32 out -------
__global__ __launch_bounds__(256) void spmm_out(const float* __restrict__ Abv,
                                                const int*   __restrict__ Abc,
                                                const bf16*  __restrict__ Zbt,  // [BRQ,64,16]
                                                const float* __restrict__ bias, // [64]
                                                float* __restrict__ out) {      // [N,64] f32
  const int wave = threadIdx.x >> 6;
  const int b    = blockIdx.x * 4 + wave;   // one block-row per wave
  const int lane = threadIdx.x & 63;
  const int l15  = lane & 15;
  const int quad = lane >> 4;

  const int*   bc    = Abc + b * KNZ;
  const int    cst   = (quad & 1) * 8;
  const int    half  = quad >> 1;
  const float* abase = Abv + (long)b * (KNZ * 256) + l15 * 16 + cst;

  bf16x8 afr[4];
  long   zb[4];
#pragma unroll
  for (int kp = 0; kp < 4; ++kp) {
    int blk = 2 * kp + half;
    afr[kp] = load8(abase + blk * 256);
    zb[kp]  = (long)bc[blk] * (NCLS * 16) + cst;
  }
  bf16x8 bfr[4][4];
#pragma unroll
  for (int kp = 0; kp < 4; ++kp)
#pragma unroll
    for (int t = 0; t < 4; ++t) {
      int f = t * 16 + l15;
      bfr[kp][t] = *(const bf16x8*)(Zbt + zb[kp] + f * 16);
    }

  f32x4 acc[4] = {};
#pragma unroll
  for (int kp = 0; kp < 4; ++kp)
#pragma unroll
    for (int t = 0; t < 4; ++t)
      acc[t] = mfma16(afr[kp], bfr[kp][t], acc[t]);

#pragma unroll
  for (int t = 0; t < 4; ++t) {
    int f = t * 16 + l15;
    float bi = bias[f];
#pragma unroll
    for (int i = 0; i < 4; ++i) {
      out[(long)(b * 16 + quad * 4 + i) * NCLS + f] = acc[t][i] + bi;
    }
  }
}

extern "C" void kernel_launch(void* const* d_in, const int* in_sizes, int n_in,
                              void* d_out, int out_size, void* d_ws, size_t ws_size,
                              hipStream_t stream) {
  const float* features = (const float*)d_in[0];
  const float* bvals    = (const float*)d_in[1];
  const float* W0       = (const float*)d_in[2];
  const float* b0       = (const float*)d_in[3];
  const float* W1       = (const float*)d_in[4];
  const float* b1       = (const float*)d_in[5];
  const float* W2       = (const float*)d_in[6];
  const float* b2       = (const float*)d_in[7];
  const float* g0       = (const float*)d_in[8];
  const float* beta0    = (const float*)d_in[9];
  const float* g1       = (const float*)d_in[10];
  const float* beta1    = (const float*)d_in[11];
  const int*   bcols    = (const int*)d_in[12];
  float* outp = (float*)d_out;

  // d_ws: zbt [N*HID] + h [N*HID] bf16 = exactly 128 MiB.
  bf16* zbt = (bf16*)d_ws;
  bf16* h   = zbt + (size_t)N_NODES * HID;

  // Transposed bf16 weights in d_out-as-scratch (229 KB of the 33.6 MB f32 output
  // buffer). All reads complete before spmm_out overwrites d_out (stream order).
  bf16* w0t = (bf16*)d_out;         // IN_F*HID  = 32768 elems
  bf16* w1t = w0t + IN_F * HID;     // HID*HID   = 65536 elems
  bf16* w2t = w1t + HID * HID;      // HID*NCLS  = 16384 elems

  transpose_all<<<dim3(448), dim3(256), 0, stream>>>(W0, W1, W2, w0t, w1t, w2t);

  // layer 0: 1024 blocks, CG=4 -> 8 row-tiles/wave
  gemm_bt<float, IN_F, HID, 1024><<<dim3(1024), dim3(256), 0, stream>>>(features, w0t, zbt);
  spmm_ln<<<dim3(BRQ / RPW), dim3(256), 0, stream>>>(bvals, bcols, zbt, b0, g0, beta0, h);
  // layer 1
  gemm_bt<bf16, HID, HID, 1024><<<dim3(1024), dim3(256), 0, stream>>>(h, w1t, zbt);
  spmm_ln<<<dim3(BRQ / RPW), dim3(256), 0, stream>>>(bvals, bcols, zbt, b1, g1, beta1, h);
  // output layer: CG=1, 512 blocks -> 4 row-tiles/wave
  gemm_bt<bf16, HID, NCLS, 512><<<dim3(512), dim3(256), 0, stream>>>(h, w2t, zbt);
  spmm_out<<<dim3(BRQ / 4), dim3(256), 0, stream>>>(bvals, bcols, zbt, b2, outp);
}

// Round 3
// 463.885 us; speedup vs baseline: 1.0150x; 1.0150x over previous
//
#include <hip/hip_runtime.h>
#include <hip/hip_bf16.h>

// GCN over Block-CSR adjacency. ALL I/O BUFFERS ARE FLOAT32 (reference dtypes).
// Compute: bf16 MFMA, fp32 accumulate; intermediates stored bf16.
//
// Round 9: FUSED layers. Evidence R6/R7/R8: spmm_ln is pinned at FETCH~283MB,
// 3.4-3.8 TB/s effective for the gather mix regardless of schedule (reg-serial,
// reg-pipelined, LDS-DMA all converge). So stop scheduling, cut bytes:
// A@(XW) = (A@X)W. Fuse the dense W-multiply into the spmm kernel:
//  - gather X/h blocks directly (same [F][16] blocked-transposed layout, same
//    gather traffic), S = A@X per block-row, then S@W with W in REGISTERS
//    (B-stationary per wave, loaded once per WG, L2-resident).
//  - deletes: 3x gemm_bt, transpose_all, zbt (2x 64MB write + 64MB-unique
//    gather-read round-trips) => ~190us of streaming traffic and dispatches.
//  - S kept at ~f32 precision via hi/lo bf16 split (2x dense MFMA, compute is
//    3% utilized -> free). Rounding count matches old zbt path.
//  - S redistributed across waves via LDS ([16][F] padded); 2 raw lgkm-only
//    barriers per row (vm gather queue stays in flight across barriers).
//  - dense phase (32-64 MFMA + ds_reads) doubles as the latency-hiding window
//    for next-row gathers (issued pre-barrier), which standalone spmm_ln lacked.
//
// ws layout: fbt [0,32MiB) (dead after L0), hA [64,128), hB [0,64) = 128 MiB.
// d_out untouched until the final fused layer writes it.

typedef __bf16 bf16;
typedef bf16 bf16x8 __attribute__((ext_vector_type(8)));
typedef bf16 bf16x4 __attribute__((ext_vector_type(4)));
typedef float f32x4 __attribute__((ext_vector_type(4)));

#define N_NODES 131072
#define BRQ 8192      // block rows (= N/16)
#define KNZ 8         // nonzero blocks per block row
#define IN_F 128
#define HID 256
#define NCLS 64
#define NROWS 8       // block-rows per workgroup

#define SB() __builtin_amdgcn_sched_barrier(0)

static __device__ __forceinline__ f32x4 mfma16(bf16x8 a, bf16x8 b, f32x4 c) {
  return __builtin_amdgcn_mfma_f32_16x16x32_bf16(a, b, c, 0, 0, 0);
}

static __device__ __forceinline__ bf16x8 cvt8(f32x4 a0, f32x4 a1) {
  bf16x8 r;
  r[0] = (bf16)a0[0]; r[1] = (bf16)a0[1]; r[2] = (bf16)a0[2]; r[3] = (bf16)a0[3];
  r[4] = (bf16)a1[0]; r[5] = (bf16)a1[1]; r[6] = (bf16)a1[2]; r[7] = (bf16)a1[3];
  return r;
}

// ---------------- features -> blocked-transposed bf16 [BRQ][128][16] -------------
__global__ __launch_bounds__(256) void prep_fbt(const float* __restrict__ F,
                                                bf16* __restrict__ out) {
  __shared__ float T[16][132];
  const int b = blockIdx.x, tid = threadIdx.x;
#pragma unroll
  for (int p = 0; p < 2; ++p) {
    int ci = tid + p * 256;            // f32x4 chunk id (512 total)
    int r = ci >> 5, c4 = ci & 31;
    f32x4 v = *(const f32x4*)(F + ((long)b * 16 + r) * 128 + c4 * 4);
    *(f32x4*)&T[r][c4 * 4] = v;
  }
  __syncthreads();
  int f = tid >> 1, r0 = (tid & 1) * 8;
  bf16x8 o;
#pragma unroll
  for (int e = 0; e < 8; ++e) o[e] = (bf16)T[r0 + e][f];
  *(bf16x8*)(out + (long)b * 2048 + f * 16 + r0) = o;
}

// ---------------- fused SpMM(A, X) @ W [+bias +relu +LN] -------------------------
// WG = WAVES waves, one block-row per iteration, NROWS iterations.
// spmm: wave owns f-slice of S (TS 16-col frags); dense: wave owns n-slice of out
// (TD 16-col frags) with W^T frags in registers. S exchanged via LDS (hi/lo bf16).
template<int F_IN, int F_OUT, int WAVES, bool LN>
__global__ __launch_bounds__(WAVES * 64, 2) void fused_layer(
    const float* __restrict__ Abv, const int* __restrict__ Abc,
    const bf16* __restrict__ Xbt, const float* __restrict__ W,
    const float* __restrict__ bias, const float* __restrict__ gamma,
    const float* __restrict__ beta, bf16* __restrict__ Hbt,
    float* __restrict__ Out) {
  constexpr int TS = F_IN / (16 * WAVES);   // spmm t-frags per wave
  constexpr int TD = F_OUT / (16 * WAVES);  // dense t-frags per wave
  constexpr int KD = F_IN / 32;             // dense k-steps
  constexpr int RW = F_IN + 8;              // S row stride in bf16 (+16B pad)
  constexpr long XBLK = (long)F_IN * 32;    // gathered block bytes

  const int wave = threadIdx.x >> 6;
  const int lane = threadIdx.x & 63;
  const int l15 = lane & 15, quad = lane >> 4;
  const int cst = (quad & 1) * 8, half = quad >> 1;
  const int fsl = wave * 16 * TS;
  const int nb  = wave * 16 * TD;

  __shared__ bf16 Sh[2][16][RW];            // hi/lo planes of S
  __shared__ float LS[WAVES][16], LSS[WAVES][16];

  // dense B (W^T) fragments in registers: k = kp*32 + quad*8 + j, n-slice per wave
  bf16x8 wbf[KD][TD];
#pragma unroll
  for (int kp = 0; kp < KD; ++kp)
#pragma unroll
    for (int t = 0; t < TD; ++t) {
      const float* wp = W + (long)(kp * 32 + quad * 8) * F_OUT + nb + t * 16 + l15;
      bf16x8 v;
#pragma unroll
      for (int j = 0; j < 8; ++j) v[j] = (bf16)wp[(long)j * F_OUT];
      wbf[kp][t] = v;
    }
  float bv[TD], gv[TD], btv[TD];
#pragma unroll
  for (int t = 0; t < TD; ++t) {
    int n = nb + t * 16 + l15;
    bv[t] = bias[n];
    if constexpr (LN) { gv[t] = gamma[n]; btv[t] = beta[n]; }
  }

  const int b0 = blockIdx.x * NROWS;
  const char* zb = (const char*)Xbt;
  const unsigned fo0 = (unsigned)((fsl + l15) * 32 + cst * 2);

  // ---- prologue: row b0 gathers + A loads; bc for row b0+1 ----
  int bcc[4];
  bf16x8 bfr[4][TS];
  f32x4 araw[4][2];
  {
    const int* bc = Abc + b0 * KNZ;
#pragma unroll
    for (int kp = 0; kp < 4; ++kp) {
      long zo = (long)bc[2 * kp + half] * XBLK;
#pragma unroll
      for (int t = 0; t < TS; ++t)
        bfr[kp][t] = *(const bf16x8*)(zb + zo + fo0 + (unsigned)t * 512);
    }
    const float* ab = Abv + (long)b0 * (KNZ * 256) + l15 * 16 + cst;
#pragma unroll
    for (int kp = 0; kp < 4; ++kp) {
      const float* p = ab + (2 * kp + half) * 256;
      araw[kp][0] = *(const f32x4*)p;
      araw[kp][1] = *(const f32x4*)(p + 4);
    }
    if (NROWS > 1) {
      const int* bc1 = Abc + (b0 + 1) * KNZ;
#pragma unroll
      for (int kp = 0; kp < 4; ++kp) bcc[kp] = bc1[2 * kp + half];
    }
  }

#pragma unroll
  for (int it = 0; it < NROWS; ++it) {
    const int b = b0 + it;
    // A frags for this row (raw f32 loaded one row ago)
    bf16x8 afr[4];
#pragma unroll
    for (int kp = 0; kp < 4; ++kp) afr[kp] = cvt8(araw[kp][0], araw[kp][1]);
    // bc two rows ahead (full row to cover scalar-load latency)
    int bcn[4];
    if (it + 2 < NROWS) {
      const int* bc = Abc + (b + 2) * KNZ;
#pragma unroll
      for (int kp = 0; kp < 4; ++kp) bcn[kp] = bc[2 * kp + half];
    }
    // ---- spmm: S = A @ X_gathered ----
    f32x4 sacc[TS] = {};
#pragma unroll
    for (int kp = 0; kp < 4; ++kp)
#pragma unroll
      for (int t = 0; t < TS; ++t)
        sacc[t] = mfma16(afr[kp], bfr[kp][t], sacc[t]);
    SB();
    // ---- S -> hi/lo bf16 into LDS ----
#pragma unroll
    for (int t = 0; t < TS; ++t) {
      int f = fsl + t * 16 + l15;
#pragma unroll
      for (int i = 0; i < 4; ++i) {
        float s = sacc[t][i];
        bf16 hi = (bf16)s;
        bf16 lo = (bf16)(s - (float)hi);
        int r = quad * 4 + i;
        Sh[0][r][f] = hi;
        Sh[1][r][f] = lo;
      }
    }
    SB();
    // ---- issue next-row gathers + A loads BEFORE the barrier ----
    if (it + 1 < NROWS) {
#pragma unroll
      for (int kp = 0; kp < 4; ++kp) {
        long zo = (long)bcc[kp] * XBLK;
#pragma unroll
        for (int t = 0; t < TS; ++t)
          bfr[kp][t] = *(const bf16x8*)(zb + zo + fo0 + (unsigned)t * 512);
      }
      const float* ab = Abv + (long)(b + 1) * (KNZ * 256) + l15 * 16 + cst;
#pragma unroll
      for (int kp = 0; kp < 4; ++kp) {
        const float* p = ab + (2 * kp + half) * 256;
        araw[kp][0] = *(const f32x4*)p;
        araw[kp][1] = *(const f32x4*)(p + 4);
      }
      if (it + 2 < NROWS) {
#pragma unroll
        for (int kp = 0; kp < 4; ++kp) bcc[kp] = bcn[kp];
      }
    }
    SB();
    // raw barrier: drain LDS writes only; gather queue stays alive.
    asm volatile("s_waitcnt lgkmcnt(0)" ::: "memory");
    __builtin_amdgcn_s_barrier();
    SB();
    // ---- dense: out = S @ W (hi + lo planes) ----
    f32x4 dacc[TD] = {};
#pragma unroll
    for (int kp = 0; kp < KD; ++kp) {
      bf16x8 shi = *(const bf16x8*)&Sh[0][l15][kp * 32 + quad * 8];
      bf16x8 slo = *(const bf16x8*)&Sh[1][l15][kp * 32 + quad * 8];
#pragma unroll
      for (int t = 0; t < TD; ++t) {
        dacc[t] = mfma16(shi, wbf[kp][t], dacc[t]);
        dacc[t] = mfma16(slo, wbf[kp][t], dacc[t]);
      }
    }
    SB();
    if constexpr (LN) {
      // bias + relu + LayerNorm over F_OUT (cross-wave combine)
      float ps[4] = {0.f, 0.f, 0.f, 0.f}, pss[4] = {0.f, 0.f, 0.f, 0.f};
#pragma unroll
      for (int t = 0; t < TD; ++t)
#pragma unroll
        for (int i = 0; i < 4; ++i) {
          float v = dacc[t][i] + bv[t];
          v = v > 0.f ? v : 0.f;
          dacc[t][i] = v;
          ps[i] += v;
          pss[i] += v * v;
        }
#pragma unroll
      for (int m = 1; m < 16; m <<= 1)
#pragma unroll
        for (int i = 0; i < 4; ++i) {
          ps[i]  += __shfl_xor(ps[i], m, 64);
          pss[i] += __shfl_xor(pss[i], m, 64);
        }
      if (l15 == 0)
#pragma unroll
        for (int i = 0; i < 4; ++i) {
          LS[wave][quad * 4 + i]  = ps[i];
          LSS[wave][quad * 4 + i] = pss[i];
        }
      SB();
      asm volatile("s_waitcnt lgkmcnt(0)" ::: "memory");
      __builtin_amdgcn_s_barrier();
      SB();
      float mu[4], rstd[4];
#pragma unroll
      for (int i = 0; i < 4; ++i) {
        int r = quad * 4 + i;
        float s = 0.f, ss = 0.f;
#pragma unroll
        for (int w = 0; w < WAVES; ++w) { s += LS[w][r]; ss += LSS[w][r]; }
        mu[i] = s * (1.f / F_OUT);
        float var = ss * (1.f / F_OUT) - mu[i] * mu[i];
        rstd[i] = rsqrtf(var + 1e-5f);
      }
      bf16* hb = Hbt + (long)b * (F_OUT * 16);
#pragma unroll
      for (int t = 0; t < TD; ++t) {
        int n = nb + t * 16 + l15;
        bf16x4 o;
#pragma unroll
        for (int i = 0; i < 4; ++i)
          o[i] = (bf16)((dacc[t][i] - mu[i]) * rstd[i] * gv[t] + btv[t]);
        *(bf16x4*)(hb + n * 16 + quad * 4) = o;
      }
    } else {
      // output layer: bias only, f32 row-major [N, NCLS]
#pragma unroll
      for (int t = 0; t < TD; ++t) {
        int n = nb + t * 16 + l15;
#pragma unroll
        for (int i = 0; i < 4; ++i)
          Out[((long)b * 16 + quad * 4 + i) * NCLS + n] = dacc[t][i] + bv[t];
      }
    }
    SB();
  }
}

extern "C" void kernel_launch(void* const* d_in, const int* in_sizes, int n_in,
                              void* d_out, int out_size, void* d_ws, size_t ws_size,
                              hipStream_t stream) {
  const float* features = (const float*)d_in[0];
  const float* bvals    = (const float*)d_in[1];
  const float* W0       = (const float*)d_in[2];
  const float* b0       = (const float*)d_in[3];
  const float* W1       = (const float*)d_in[4];
  const float* b1       = (const float*)d_in[5];
  const float* W2       = (const float*)d_in[6];
  const float* b2       = (const float*)d_in[7];
  const float* g0       = (const float*)d_in[8];
  const float* beta0    = (const float*)d_in[9];
  const float* g1       = (const float*)d_in[10];
  const float* beta1    = (const float*)d_in[11];
  const int*   bcols    = (const int*)d_in[12];
  float* outp = (float*)d_out;

  // ws: fbt [0,32MiB) (dead after L0); hB [0,64MiB); hA [64,128MiB). 128 MiB total.
  bf16* fbt = (bf16*)d_ws;                          // [BRQ][128][16]
  bf16* hB  = (bf16*)d_ws;                          // [BRQ][256][16]
  bf16* hA  = (bf16*)d_ws + (size_t)N_NODES * HID;  // [BRQ][256][16]

  prep_fbt<<<dim3(BRQ), dim3(256), 0, stream>>>(features, fbt);
  // layer 0: h0 = LN(relu((A@f) @ W0 + b0))
  fused_layer<IN_F, HID, 8, true><<<dim3(BRQ / NROWS), dim3(512), 0, stream>>>(
      bvals, bcols, fbt, W0, b0, g0, beta0, hA, nullptr);
  // layer 1: h1 = LN(relu((A@h0) @ W1 + b1))
  fused_layer<HID, HID, 8, true><<<dim3(BRQ / NROWS), dim3(512), 0, stream>>>(
      bvals, bcols, hA, W1, b1, g1, beta1, hB, nullptr);
  // output layer: out = (A@h1) @ W2 + b2   (f32 row-major)
  fused_layer<HID, NCLS, 4, false><<<dim3(BRQ / NROWS), dim3(256), 0, stream>>>(
      bvals, bcols, hB, W2, b2, nullptr, nullptr, nullptr, outp);
}